// Round 14
// baseline (123.089 us; speedup 1.0000x reference)
//
#include <hip/hip_runtime.h>
#include <math.h>
#include <float.h>

// Zonotope distance + gradient.
// R14 = R13 with 64-thread blocks (1 wave/block, WPB=1). The kernel has no
// inter-wave communication (wave-private LDS, no __syncthreads), so 1-wave
// blocks let the CU scheduler pack/retire waves per-SIMD at finer grain.
// Math byte-identical to R13/R12. ALL FP op orders match the numpy
// reference exactly (contract(off); no FMA; packed per-half IEEE identical).

typedef float f32x2 __attribute__((ext_vector_type(2)));
typedef float f32x4 __attribute__((ext_vector_type(4)));
typedef float f4u   __attribute__((ext_vector_type(4), aligned(4)));
typedef unsigned long long u64;
typedef unsigned int u32;

constexpr int H = 48;
constexpr int V = 96;
constexpr int PPW = 4;            // points per wave
constexpr float ZEPS = 1e-4f;

__device__ __forceinline__ f32x2 pkmul(f32x2 a, f32x2 b) {
  f32x2 d;
  asm("v_pk_mul_f32 %0, %1, %2" : "=v"(d) : "v"(a), "v"(b));
  return d;
}
__device__ __forceinline__ f32x2 pkadd(f32x2 a, f32x2 b) {
  f32x2 d;
  asm("v_pk_add_f32 %0, %1, %2" : "=v"(d) : "v"(a), "v"(b));
  return d;
}
// a - b per half (add of negated src1; IEEE-exact)
__device__ __forceinline__ f32x2 pksub(f32x2 a, f32x2 b) {
  f32x2 d;
  asm("v_pk_add_f32 %0, %1, %2 neg_lo:[0,1] neg_hi:[0,1]" : "=v"(d) : "v"(a), "v"(b));
  return d;
}
__device__ __forceinline__ float max3f(float a, float b, float c) {
  float d;
  asm("v_max3_f32 %0, %1, %2, %3" : "=v"(d) : "v"(a), "v"(b), "v"(c));
  return d;
}

__global__ __launch_bounds__(64, 8) void zono_dist_kernel(
    const float* __restrict__ point,   // [N,3]
    const float* __restrict__ Ag,      // [N,H,3]
    const float* __restrict__ bg,      // [N,H]
    const float* __restrict__ v1g,     // [N,V,3]
    const float* __restrict__ v2g,     // [N,V,3]
    float* __restrict__ out,           // [N] dist ++ [N,3] grad
    int N)
{
#pragma clang fp contract(off)
  // q storage: [comp][group][56]; group bases are banks {0,24,16,8},
  // 4-bank spans per b128 read -> disjoint across groups, conflict-free.
  __shared__ __align__(16) float sQ[3][PPW][56];

  const int lane = threadIdx.x & 63;
  const int g = lane >> 4;          // group (point within wave)
  const int j = lane & 15;          // lane within group
  int n = blockIdx.x * PPW + g;
  if (n >= N) n = N - 1;            // duplicate work, duplicate-same writes

  // ---- loads ----
  const float px = point[3 * (size_t)n + 0];
  const float py = point[3 * (size_t)n + 1];
  const float pz = point[3 * (size_t)n + 2];

  const float* ap = Ag + (size_t)n * (H * 3) + 9 * j;   // planes 3j..3j+2
  f4u A0 = *(const f4u*)(ap);        // a0x a0y a0z a1x
  f4u A1 = *(const f4u*)(ap + 4);    // a1y a1z a2x a2y
  const float a2z = ap[8];
  const float* bp = bg + (size_t)n * H + 3 * j;
  const float b0 = bp[0], b1 = bp[1], b2 = bp[2];

  // edges 6j..6j+5: 18 floats per endpoint array, issued early
  const float* e1p = v1g + (size_t)n * (V * 3) + 18 * j;
  const float* e2p = v2g + (size_t)n * (V * 3) + 18 * j;
  f4u Ea = *(const f4u*)(e1p);      f4u Eb = *(const f4u*)(e1p + 4);
  f4u Ec = *(const f4u*)(e1p + 8);  f4u Ed = *(const f4u*)(e1p + 12);
  f32x2 Ee = *(const f32x2*)(e1p + 16);
  f4u Fa = *(const f4u*)(e2p);      f4u Fb = *(const f4u*)(e2p + 4);
  f4u Fc = *(const f4u*)(e2p + 8);  f4u Fd = *(const f4u*)(e2p + 12);
  f32x2 Fe = *(const f32x2*)(e2p + 16);

  const float ax0 = A0.x, ay0 = A0.y, az0 = A0.z;
  const float ax1 = A0.w, ay1 = A1.x, az1 = A1.y;
  const float ax2 = A1.z, ay2 = A1.w, az2 = a2z;

  // ---- signed facet offsets + projections (exact ref op order) ----
  const float apb0 = ((ax0 * px + ay0 * py) + az0 * pz) - b0;
  const float apb1 = ((ax1 * px + ay1 * py) + az1 * pz) - b1;
  const float apb2 = ((ax2 * px + ay2 * py) + az2 * pz) - b2;
  const float q0x = px - apb0 * ax0, q0y = py - apb0 * ay0, q0z = pz - apb0 * az0;
  const float q1x = px - apb1 * ax1, q1y = py - apb1 * ay1, q1z = pz - apb1 * az1;
  const float q2x = px - apb2 * ax2, q2y = py - apb2 * ay2, q2z = pz - apb2 * az2;

  float* qxw = &sQ[0][g][0];
  float* qyw = &sQ[1][g][0];
  float* qzw = &sQ[2][g][0];
  qxw[3 * j + 0] = q0x; qxw[3 * j + 1] = q1x; qxw[3 * j + 2] = q2x;
  qyw[3 * j + 0] = q0y; qyw[3 * j + 1] = q1y; qyw[3 * j + 2] = q2y;
  qzw[3 * j + 0] = q0z; qzw[3 * j + 1] = q1z; qzw[3 * j + 2] = q2z;

  // ---- is_neg per group ----
  const u64 bneg = __ballot(max3f(apb0, apb1, apb2) <= 0.0f);
  u32 negbits = 0;
  if ((bneg & 0x000000000000FFFFull) == 0x000000000000FFFFull) negbits |= 1;
  if ((bneg & 0x00000000FFFF0000ull) == 0x00000000FFFF0000ull) negbits |= 2;
  if ((bneg & 0x0000FFFF00000000ull) == 0x0000FFFF00000000ull) negbits |= 4;
  if ((bneg & 0xFFFF000000000000ull) == 0xFFFF000000000000ull) negbits |= 8;

  // ---- prebuilt broadcast pairs (loop-invariant) ----
  const f32x2 AX0 = {ax0, ax0}, AY0 = {ay0, ay0}, AZ0 = {az0, az0}, PB0 = {b0, b0};
  const f32x2 AX1 = {ax1, ax1}, AY1 = {ay1, ay1}, AZ1 = {az1, az1}, PB1 = {b1, b1};
  const f32x2 AX2 = {ax2, ax2}, AY2 = {ay2, ay2}, AZ2 = {az2, az2}, PB2 = {b2, b2};

  // ---- H^2 check: 12 iterations, 2 h-pairs (4 candidates) each ----
  u64 bad0 = 0, bad1 = 0, bad2 = 0, bad3 = 0;   // uniform, per group
  const f32x4* qx4 = (const f32x4*)qxw;
  const f32x4* qy4 = (const f32x4*)qyw;
  const f32x4* qz4 = (const f32x4*)qzw;
  #pragma unroll
  for (int it = 0; it < 12; ++it) {
    const f32x4 X = qx4[it], Y = qy4[it], Z = qz4[it];   // b128 broadcasts
    const f32x2 xlo = __builtin_shufflevector(X, X, 0, 1);
    const f32x2 xhi = __builtin_shufflevector(X, X, 2, 3);
    const f32x2 ylo = __builtin_shufflevector(Y, Y, 0, 1);
    const f32x2 yhi = __builtin_shufflevector(Y, Y, 2, 3);
    const f32x2 zlo = __builtin_shufflevector(Z, Z, 0, 1);
    const f32x2 zhi = __builtin_shufflevector(Z, Z, 2, 3);
    // lo pair: candidates h = 4it, 4it+1
    f32x2 s0 = pksub(pkadd(pkadd(pkmul(AX0, xlo), pkmul(AY0, ylo)), pkmul(AZ0, zlo)), PB0);
    f32x2 s1 = pksub(pkadd(pkadd(pkmul(AX1, xlo), pkmul(AY1, ylo)), pkmul(AZ1, zlo)), PB1);
    f32x2 s2 = pksub(pkadd(pkadd(pkmul(AX2, xlo), pkmul(AY2, ylo)), pkmul(AZ2, zlo)), PB2);
    // hi pair: candidates h = 4it+2, 4it+3
    f32x2 t0 = pksub(pkadd(pkadd(pkmul(AX0, xhi), pkmul(AY0, yhi)), pkmul(AZ0, zhi)), PB0);
    f32x2 t1 = pksub(pkadd(pkadd(pkmul(AX1, xhi), pkmul(AY1, yhi)), pkmul(AZ1, zhi)), PB1);
    f32x2 t2 = pksub(pkadd(pkadd(pkmul(AX2, xhi), pkmul(AY2, yhi)), pkmul(AZ2, zhi)), PB2);
    const u64 bl0 = __ballot(max3f(s0.x, s1.x, s2.x) <= ZEPS);
    const u64 bl1 = __ballot(max3f(s0.y, s1.y, s2.y) <= ZEPS);
    const u64 bl2 = __ballot(max3f(t0.x, t1.x, t2.x) <= ZEPS);
    const u64 bl3 = __ballot(max3f(t0.y, t1.y, t2.y) <= ZEPS);
    const int h = 4 * it;
    const u64 c0 = 1ull << h, c1 = 2ull << h, c2 = 4ull << h, c3 = 8ull << h;
    bad0 |= ((~bl0 & 0x000000000000FFFFull) ? c0 : 0) | ((~bl1 & 0x000000000000FFFFull) ? c1 : 0)
          | ((~bl2 & 0x000000000000FFFFull) ? c2 : 0) | ((~bl3 & 0x000000000000FFFFull) ? c3 : 0);
    bad1 |= ((~bl0 & 0x00000000FFFF0000ull) ? c0 : 0) | ((~bl1 & 0x00000000FFFF0000ull) ? c1 : 0)
          | ((~bl2 & 0x00000000FFFF0000ull) ? c2 : 0) | ((~bl3 & 0x00000000FFFF0000ull) ? c3 : 0);
    bad2 |= ((~bl0 & 0x0000FFFF00000000ull) ? c0 : 0) | ((~bl1 & 0x0000FFFF00000000ull) ? c1 : 0)
          | ((~bl2 & 0x0000FFFF00000000ull) ? c2 : 0) | ((~bl3 & 0x0000FFFF00000000ull) ? c3 : 0);
    bad3 |= ((~bl0 & 0xFFFF000000000000ull) ? c0 : 0) | ((~bl1 & 0xFFFF000000000000ull) ? c1 : 0)
          | ((~bl2 & 0xFFFF000000000000ull) ? c2 : 0) | ((~bl3 & 0xFFFF000000000000ull) ? c3 : 0);
  }
  const u64 MASK48 = (1ull << H) - 1;
  const bool anyface = (((~bad0) | (~bad1) | (~bad2) | (~bad3)) & MASK48) != 0;

  // ---- face path (gated; rare) ----
  float fv = INFINITY, fgx = 0.f, fgy = 0.f, fgz = 0.f;
  if (anyface) {
    const u64 badg = (g == 0) ? bad0 : (g == 1) ? bad1 : (g == 2) ? bad2 : bad3;
    const u32 mb = (u32)(badg >> (3 * j));
    float p0 = INFINITY, p1 = INFINITY, p2 = INFINITY;
    if (!(mb & 1)) {
      float dx = px - q0x, dy = py - q0y, dz = pz - q0z;
      p0 = sqrtf((dx * dx + dy * dy) + dz * dz);
    }
    if (!(mb & 2)) {
      float dx = px - q1x, dy = py - q1y, dz = pz - q1z;
      p1 = sqrtf((dx * dx + dy * dy) + dz * dz);
    }
    if (!(mb & 4)) {
      float dx = px - q2x, dy = py - q2y, dz = pz - q2z;
      p2 = sqrtf((dx * dx + dy * dy) + dz * dz);
    }
    float bv = p0; int bk = 0;
    if (p1 < bv) { bv = p1; bk = 1; }
    if (p2 < bv) { bv = p2; bk = 2; }
    u64 key = ((u64)__float_as_uint(bv) << 16) | (u32)(3 * j + bk);
    #pragma unroll
    for (int off = 8; off; off >>= 1) {
      u64 o = __shfl_xor(key, off);
      if (o < key) key = o;
    }
    fv = __uint_as_float((u32)(key >> 16));
    const int ks = (int)(key & 0xFFFF);
    const int owner = 16 * g + ks / 3;
    const int ms = ks - 3 * (ks / 3);
    const float sx0 = __shfl(ax0, owner), sx1 = __shfl(ax1, owner), sx2 = __shfl(ax2, owner);
    const float sy0 = __shfl(ay0, owner), sy1 = __shfl(ay1, owner), sy2 = __shfl(ay2, owner);
    const float sz0 = __shfl(az0, owner), sz1 = __shfl(az1, owner), sz2 = __shfl(az2, owner);
    fgx = (ms == 0) ? sx0 : (ms == 1) ? sx1 : sx2;
    fgy = (ms == 0) ? sy0 : (ms == 1) ? sy1 : sy2;
    fgz = (ms == 0) ? sz0 : (ms == 1) ? sz1 : sz2;
  }

  // ---- inside-zonotope path (gated; rare) ----
  float nv = 0.f, ngx = 0.f, ngy = 0.f, ngz = 0.f;
  if (negbits) {
    float bv = apb0; int bk = 0;                  // strict > keeps first k
    if (apb1 > bv) { bv = apb1; bk = 1; }
    if (apb2 > bv) { bv = apb2; bk = 2; }
    u32 bits = __float_as_uint(bv);
    u32 obits = (bits >> 31) ? ~bits : (bits | 0x80000000u);   // monotone
    u64 key = ((u64)obits << 16) | (u32)(0xFFFF - (3 * j + bk));
    #pragma unroll
    for (int off = 8; off; off >>= 1) {
      u64 o = __shfl_xor(key, off);
      if (o > key) key = o;
    }
    const int ks = (int)(0xFFFF - (key & 0xFFFF));
    const int owner = 16 * g + ks / 3;
    const int ms = ks - 3 * (ks / 3);
    const float v0 = __shfl(apb0, owner), v1 = __shfl(apb1, owner), v2 = __shfl(apb2, owner);
    nv = (ms == 0) ? v0 : (ms == 1) ? v1 : v2;
    const float sx0 = __shfl(ax0, owner), sx1 = __shfl(ax1, owner), sx2 = __shfl(ax2, owner);
    const float sy0 = __shfl(ay0, owner), sy1 = __shfl(ay1, owner), sy2 = __shfl(ay2, owner);
    const float sz0 = __shfl(az0, owner), sz1 = __shfl(az1, owner), sz2 = __shfl(az2, owner);
    ngx = (ms == 0) ? sx0 : (ms == 1) ? sx1 : sx2;
    ngy = (ms == 0) ? sy0 : (ms == 1) ? sy1 : sy2;
    ngz = (ms == 0) ? sz0 : (ms == 1) ? sz1 : sz2;
  }

  // ---- edge distances: 3 packed pairs (edges 2t,2t+1), exact ref math ----
  float bed = INFINITY, bvx = 0.f, bvy = 0.f, bvz = 0.f;
  {
    const f32x2 Px = {px, px}, Py = {py, py}, Pz = {pz, pz};
    #pragma unroll
    for (int t = 0; t < 3; ++t) {
      f32x2 X1, Y1, Z1, X2, Y2, Z2;
      if (t == 0) {
        X1 = f32x2{Ea.x, Ea.w}; Y1 = f32x2{Ea.y, Eb.x}; Z1 = f32x2{Ea.z, Eb.y};
        X2 = f32x2{Fa.x, Fa.w}; Y2 = f32x2{Fa.y, Fb.x}; Z2 = f32x2{Fa.z, Fb.y};
      } else if (t == 1) {
        X1 = f32x2{Eb.z, Ec.y}; Y1 = f32x2{Eb.w, Ec.z}; Z1 = f32x2{Ec.x, Ec.w};
        X2 = f32x2{Fb.z, Fc.y}; Y2 = f32x2{Fb.w, Fc.z}; Z2 = f32x2{Fc.x, Fc.w};
      } else {
        X1 = f32x2{Ed.x, Ed.w}; Y1 = f32x2{Ed.y, Ee.x}; Z1 = f32x2{Ed.z, Ee.y};
        X2 = f32x2{Fd.x, Fd.w}; Y2 = f32x2{Fd.y, Fe.x}; Z2 = f32x2{Fd.z, Fe.y};
      }
      const f32x2 dx = pksub(X2, X1), dy = pksub(Y2, Y1), dz = pksub(Z2, Z1);
      const f32x2 den = pkadd(pkadd(pkmul(dx, dx), pkmul(dy, dy)), pkmul(dz, dz));
      const f32x2 wx = pksub(Px, X1), wy = pksub(Py, Y1), wz = pksub(Pz, Z1);
      const f32x2 num = pkadd(pkadd(pkmul(wx, dx), pkmul(wy, dy)), pkmul(wz, dz));
      const float th0 = num.x / den.x;             // exact IEEE divs (ref)
      const float th1 = num.y / den.y;
      const float t0 = th0 < 0.0f ? 0.0f : (th0 > 1.0f ? 1.0f : th0);
      const float t1 = th1 < 0.0f ? 0.0f : (th1 > 1.0f ? 1.0f : th1);
      const f32x2 tv = {t0, t1};
      const f32x2 Vx = pkadd(X1, pkmul(tv, dx));   // ref: v1 + t*d
      const f32x2 Vy = pkadd(Y1, pkmul(tv, dy));
      const f32x2 Vz = pkadd(Z1, pkmul(tv, dz));
      const f32x2 Ex = pksub(Px, Vx), Ey = pksub(Py, Vy), Ez = pksub(Pz, Vz);
      const f32x2 ss = pkadd(pkadd(pkmul(Ex, Ex), pkmul(Ey, Ey)), pkmul(Ez, Ez));
      const float ed0 = sqrtf(ss.x);
      const float ed1 = sqrtf(ss.y);
      const bool pick = ed1 < ed0;                 // tie -> lower index
      const float edp = pick ? ed1 : ed0;
      if (edp < bed) {                             // strict -> first index
        bed = edp;
        bvx = pick ? Vx.y : Vx.x;
        bvy = pick ? Vy.y : Vy.x;
        bvz = pick ? Vz.y : Vz.x;
      }
    }
  }
  // ---- edge reduction: f32 value-min butterfly + ballot/ctz winner ----
  float m = bed;
  #pragma unroll
  for (int off = 8; off; off >>= 1) {
    const float o = __shfl_xor(m, off);
    m = fminf(m, o);
  }
  const u64 cand = __ballot(bed == m);             // per-group fields
  const u32 gf = (u32)((cand >> (16 * g)) & 0xFFFFu);
  const int wl = 16 * g + __builtin_ctz(gf);       // first winner (index order)
  const float wvx = __shfl(bvx, wl);
  const float wvy = __shfl(bvy, wl);
  const float wvz = __shfl(bvz, wl);

  // ---- combine; lanes j=0..2 write grad comps, j=3 writes dist ----
  const bool isneg = (negbits >> g) & 1;
  const bool use_edge = (m < fv);
  const float pd = (j == 0) ? px : (j == 1) ? py : pz;
  const float wd = (j == 0) ? wvx : (j == 1) ? wvy : wvz;
  const float fd = (j == 0) ? fgx : (j == 1) ? fgy : fgz;
  const float nd = (j == 0) ? ngx : (j == 1) ? ngy : ngz;
  float dist, gnum, gden = 1.0f;
  if (isneg) {
    dist = nv; gnum = nd;
  } else if (use_edge) {
    dist = m; gnum = pd - wd; gden = m;
  } else {
    dist = fv; gnum = fd;
  }
  const float gr = gnum / gden;
  if (j < 3) out[(size_t)N + 3 * (size_t)n + j] = gr;
  if (j == 3) out[n] = dist;
}

extern "C" void kernel_launch(void* const* d_in, const int* in_sizes, int n_in,
                              void* d_out, int out_size, void* d_ws, size_t ws_size,
                              hipStream_t stream) {
  const float* point = (const float*)d_in[0];
  const float* Ag    = (const float*)d_in[1];
  const float* bg    = (const float*)d_in[2];
  const float* v1g   = (const float*)d_in[3];
  const float* v2g   = (const float*)d_in[4];
  float* out = (float*)d_out;

  const int N = in_sizes[0] / 3;
  const int blocks = (N + PPW - 1) / PPW;   // 4 points per 64-thread block
  zono_dist_kernel<<<blocks, 64, 0, stream>>>(point, Ag, bg, v1g, v2g, out, N);
}

// Round 15
// 44.580 us; speedup vs baseline: 2.7610x; 2.7610x over previous
//
#include <hip/hip_runtime.h>
#include <math.h>
#include <float.h>

// Zonotope distance + gradient.
// R15 = R13 with 64-thread blocks and __launch_bounds__(64,4) — the CLEAN
// scheduler-granularity test (R14's (64,8) cut the VGPR cap to 64->32 and
// spilled; this keeps the 128 cap so per-wave codegen matches R13 exactly).
// Math byte-identical to R13/R12. ALL FP op orders match the numpy
// reference exactly (contract(off); no FMA; packed per-half IEEE identical).

typedef float f32x2 __attribute__((ext_vector_type(2)));
typedef float f32x4 __attribute__((ext_vector_type(4)));
typedef float f4u   __attribute__((ext_vector_type(4), aligned(4)));
typedef unsigned long long u64;
typedef unsigned int u32;

constexpr int H = 48;
constexpr int V = 96;
constexpr int PPW = 4;            // points per wave
constexpr float ZEPS = 1e-4f;

__device__ __forceinline__ f32x2 pkmul(f32x2 a, f32x2 b) {
  f32x2 d;
  asm("v_pk_mul_f32 %0, %1, %2" : "=v"(d) : "v"(a), "v"(b));
  return d;
}
__device__ __forceinline__ f32x2 pkadd(f32x2 a, f32x2 b) {
  f32x2 d;
  asm("v_pk_add_f32 %0, %1, %2" : "=v"(d) : "v"(a), "v"(b));
  return d;
}
// a - b per half (add of negated src1; IEEE-exact)
__device__ __forceinline__ f32x2 pksub(f32x2 a, f32x2 b) {
  f32x2 d;
  asm("v_pk_add_f32 %0, %1, %2 neg_lo:[0,1] neg_hi:[0,1]" : "=v"(d) : "v"(a), "v"(b));
  return d;
}
__device__ __forceinline__ float max3f(float a, float b, float c) {
  float d;
  asm("v_max3_f32 %0, %1, %2, %3" : "=v"(d) : "v"(a), "v"(b), "v"(c));
  return d;
}

__global__ __launch_bounds__(64, 4) void zono_dist_kernel(
    const float* __restrict__ point,   // [N,3]
    const float* __restrict__ Ag,      // [N,H,3]
    const float* __restrict__ bg,      // [N,H]
    const float* __restrict__ v1g,     // [N,V,3]
    const float* __restrict__ v2g,     // [N,V,3]
    float* __restrict__ out,           // [N] dist ++ [N,3] grad
    int N)
{
#pragma clang fp contract(off)
  // q storage: [comp][group][56]; group bases are banks {0,24,16,8},
  // 4-bank spans per b128 read -> disjoint across groups, conflict-free.
  __shared__ __align__(16) float sQ[3][PPW][56];

  const int lane = threadIdx.x & 63;
  const int g = lane >> 4;          // group (point within wave)
  const int j = lane & 15;          // lane within group
  int n = blockIdx.x * PPW + g;
  if (n >= N) n = N - 1;            // duplicate work, duplicate-same writes

  // ---- loads ----
  const float px = point[3 * (size_t)n + 0];
  const float py = point[3 * (size_t)n + 1];
  const float pz = point[3 * (size_t)n + 2];

  const float* ap = Ag + (size_t)n * (H * 3) + 9 * j;   // planes 3j..3j+2
  f4u A0 = *(const f4u*)(ap);        // a0x a0y a0z a1x
  f4u A1 = *(const f4u*)(ap + 4);    // a1y a1z a2x a2y
  const float a2z = ap[8];
  const float* bp = bg + (size_t)n * H + 3 * j;
  const float b0 = bp[0], b1 = bp[1], b2 = bp[2];

  // edges 6j..6j+5: 18 floats per endpoint array, issued early
  const float* e1p = v1g + (size_t)n * (V * 3) + 18 * j;
  const float* e2p = v2g + (size_t)n * (V * 3) + 18 * j;
  f4u Ea = *(const f4u*)(e1p);      f4u Eb = *(const f4u*)(e1p + 4);
  f4u Ec = *(const f4u*)(e1p + 8);  f4u Ed = *(const f4u*)(e1p + 12);
  f32x2 Ee = *(const f32x2*)(e1p + 16);
  f4u Fa = *(const f4u*)(e2p);      f4u Fb = *(const f4u*)(e2p + 4);
  f4u Fc = *(const f4u*)(e2p + 8);  f4u Fd = *(const f4u*)(e2p + 12);
  f32x2 Fe = *(const f32x2*)(e2p + 16);

  const float ax0 = A0.x, ay0 = A0.y, az0 = A0.z;
  const float ax1 = A0.w, ay1 = A1.x, az1 = A1.y;
  const float ax2 = A1.z, ay2 = A1.w, az2 = a2z;

  // ---- signed facet offsets + projections (exact ref op order) ----
  const float apb0 = ((ax0 * px + ay0 * py) + az0 * pz) - b0;
  const float apb1 = ((ax1 * px + ay1 * py) + az1 * pz) - b1;
  const float apb2 = ((ax2 * px + ay2 * py) + az2 * pz) - b2;
  const float q0x = px - apb0 * ax0, q0y = py - apb0 * ay0, q0z = pz - apb0 * az0;
  const float q1x = px - apb1 * ax1, q1y = py - apb1 * ay1, q1z = pz - apb1 * az1;
  const float q2x = px - apb2 * ax2, q2y = py - apb2 * ay2, q2z = pz - apb2 * az2;

  float* qxw = &sQ[0][g][0];
  float* qyw = &sQ[1][g][0];
  float* qzw = &sQ[2][g][0];
  qxw[3 * j + 0] = q0x; qxw[3 * j + 1] = q1x; qxw[3 * j + 2] = q2x;
  qyw[3 * j + 0] = q0y; qyw[3 * j + 1] = q1y; qyw[3 * j + 2] = q2y;
  qzw[3 * j + 0] = q0z; qzw[3 * j + 1] = q1z; qzw[3 * j + 2] = q2z;

  // ---- is_neg per group ----
  const u64 bneg = __ballot(max3f(apb0, apb1, apb2) <= 0.0f);
  u32 negbits = 0;
  if ((bneg & 0x000000000000FFFFull) == 0x000000000000FFFFull) negbits |= 1;
  if ((bneg & 0x00000000FFFF0000ull) == 0x00000000FFFF0000ull) negbits |= 2;
  if ((bneg & 0x0000FFFF00000000ull) == 0x0000FFFF00000000ull) negbits |= 4;
  if ((bneg & 0xFFFF000000000000ull) == 0xFFFF000000000000ull) negbits |= 8;

  // ---- prebuilt broadcast pairs (loop-invariant) ----
  const f32x2 AX0 = {ax0, ax0}, AY0 = {ay0, ay0}, AZ0 = {az0, az0}, PB0 = {b0, b0};
  const f32x2 AX1 = {ax1, ax1}, AY1 = {ay1, ay1}, AZ1 = {az1, az1}, PB1 = {b1, b1};
  const f32x2 AX2 = {ax2, ax2}, AY2 = {ay2, ay2}, AZ2 = {az2, az2}, PB2 = {b2, b2};

  // ---- H^2 check: 12 iterations, 2 h-pairs (4 candidates) each ----
  u64 bad0 = 0, bad1 = 0, bad2 = 0, bad3 = 0;   // uniform, per group
  const f32x4* qx4 = (const f32x4*)qxw;
  const f32x4* qy4 = (const f32x4*)qyw;
  const f32x4* qz4 = (const f32x4*)qzw;
  #pragma unroll
  for (int it = 0; it < 12; ++it) {
    const f32x4 X = qx4[it], Y = qy4[it], Z = qz4[it];   // b128 broadcasts
    const f32x2 xlo = __builtin_shufflevector(X, X, 0, 1);
    const f32x2 xhi = __builtin_shufflevector(X, X, 2, 3);
    const f32x2 ylo = __builtin_shufflevector(Y, Y, 0, 1);
    const f32x2 yhi = __builtin_shufflevector(Y, Y, 2, 3);
    const f32x2 zlo = __builtin_shufflevector(Z, Z, 0, 1);
    const f32x2 zhi = __builtin_shufflevector(Z, Z, 2, 3);
    // lo pair: candidates h = 4it, 4it+1
    f32x2 s0 = pksub(pkadd(pkadd(pkmul(AX0, xlo), pkmul(AY0, ylo)), pkmul(AZ0, zlo)), PB0);
    f32x2 s1 = pksub(pkadd(pkadd(pkmul(AX1, xlo), pkmul(AY1, ylo)), pkmul(AZ1, zlo)), PB1);
    f32x2 s2 = pksub(pkadd(pkadd(pkmul(AX2, xlo), pkmul(AY2, ylo)), pkmul(AZ2, zlo)), PB2);
    // hi pair: candidates h = 4it+2, 4it+3
    f32x2 t0 = pksub(pkadd(pkadd(pkmul(AX0, xhi), pkmul(AY0, yhi)), pkmul(AZ0, zhi)), PB0);
    f32x2 t1 = pksub(pkadd(pkadd(pkmul(AX1, xhi), pkmul(AY1, yhi)), pkmul(AZ1, zhi)), PB1);
    f32x2 t2 = pksub(pkadd(pkadd(pkmul(AX2, xhi), pkmul(AY2, yhi)), pkmul(AZ2, zhi)), PB2);
    const u64 bl0 = __ballot(max3f(s0.x, s1.x, s2.x) <= ZEPS);
    const u64 bl1 = __ballot(max3f(s0.y, s1.y, s2.y) <= ZEPS);
    const u64 bl2 = __ballot(max3f(t0.x, t1.x, t2.x) <= ZEPS);
    const u64 bl3 = __ballot(max3f(t0.y, t1.y, t2.y) <= ZEPS);
    const int h = 4 * it;
    const u64 c0 = 1ull << h, c1 = 2ull << h, c2 = 4ull << h, c3 = 8ull << h;
    bad0 |= ((~bl0 & 0x000000000000FFFFull) ? c0 : 0) | ((~bl1 & 0x000000000000FFFFull) ? c1 : 0)
          | ((~bl2 & 0x000000000000FFFFull) ? c2 : 0) | ((~bl3 & 0x000000000000FFFFull) ? c3 : 0);
    bad1 |= ((~bl0 & 0x00000000FFFF0000ull) ? c0 : 0) | ((~bl1 & 0x00000000FFFF0000ull) ? c1 : 0)
          | ((~bl2 & 0x00000000FFFF0000ull) ? c2 : 0) | ((~bl3 & 0x00000000FFFF0000ull) ? c3 : 0);
    bad2 |= ((~bl0 & 0x0000FFFF00000000ull) ? c0 : 0) | ((~bl1 & 0x0000FFFF00000000ull) ? c1 : 0)
          | ((~bl2 & 0x0000FFFF00000000ull) ? c2 : 0) | ((~bl3 & 0x0000FFFF00000000ull) ? c3 : 0);
    bad3 |= ((~bl0 & 0xFFFF000000000000ull) ? c0 : 0) | ((~bl1 & 0xFFFF000000000000ull) ? c1 : 0)
          | ((~bl2 & 0xFFFF000000000000ull) ? c2 : 0) | ((~bl3 & 0xFFFF000000000000ull) ? c3 : 0);
  }
  const u64 MASK48 = (1ull << H) - 1;
  const bool anyface = (((~bad0) | (~bad1) | (~bad2) | (~bad3)) & MASK48) != 0;

  // ---- face path (gated; rare) ----
  float fv = INFINITY, fgx = 0.f, fgy = 0.f, fgz = 0.f;
  if (anyface) {
    const u64 badg = (g == 0) ? bad0 : (g == 1) ? bad1 : (g == 2) ? bad2 : bad3;
    const u32 mb = (u32)(badg >> (3 * j));
    float p0 = INFINITY, p1 = INFINITY, p2 = INFINITY;
    if (!(mb & 1)) {
      float dx = px - q0x, dy = py - q0y, dz = pz - q0z;
      p0 = sqrtf((dx * dx + dy * dy) + dz * dz);
    }
    if (!(mb & 2)) {
      float dx = px - q1x, dy = py - q1y, dz = pz - q1z;
      p1 = sqrtf((dx * dx + dy * dy) + dz * dz);
    }
    if (!(mb & 4)) {
      float dx = px - q2x, dy = py - q2y, dz = pz - q2z;
      p2 = sqrtf((dx * dx + dy * dy) + dz * dz);
    }
    float bv = p0; int bk = 0;
    if (p1 < bv) { bv = p1; bk = 1; }
    if (p2 < bv) { bv = p2; bk = 2; }
    u64 key = ((u64)__float_as_uint(bv) << 16) | (u32)(3 * j + bk);
    #pragma unroll
    for (int off = 8; off; off >>= 1) {
      u64 o = __shfl_xor(key, off);
      if (o < key) key = o;
    }
    fv = __uint_as_float((u32)(key >> 16));
    const int ks = (int)(key & 0xFFFF);
    const int owner = 16 * g + ks / 3;
    const int ms = ks - 3 * (ks / 3);
    const float sx0 = __shfl(ax0, owner), sx1 = __shfl(ax1, owner), sx2 = __shfl(ax2, owner);
    const float sy0 = __shfl(ay0, owner), sy1 = __shfl(ay1, owner), sy2 = __shfl(ay2, owner);
    const float sz0 = __shfl(az0, owner), sz1 = __shfl(az1, owner), sz2 = __shfl(az2, owner);
    fgx = (ms == 0) ? sx0 : (ms == 1) ? sx1 : sx2;
    fgy = (ms == 0) ? sy0 : (ms == 1) ? sy1 : sy2;
    fgz = (ms == 0) ? sz0 : (ms == 1) ? sz1 : sz2;
  }

  // ---- inside-zonotope path (gated; rare) ----
  float nv = 0.f, ngx = 0.f, ngy = 0.f, ngz = 0.f;
  if (negbits) {
    float bv = apb0; int bk = 0;                  // strict > keeps first k
    if (apb1 > bv) { bv = apb1; bk = 1; }
    if (apb2 > bv) { bv = apb2; bk = 2; }
    u32 bits = __float_as_uint(bv);
    u32 obits = (bits >> 31) ? ~bits : (bits | 0x80000000u);   // monotone
    u64 key = ((u64)obits << 16) | (u32)(0xFFFF - (3 * j + bk));
    #pragma unroll
    for (int off = 8; off; off >>= 1) {
      u64 o = __shfl_xor(key, off);
      if (o > key) key = o;
    }
    const int ks = (int)(0xFFFF - (key & 0xFFFF));
    const int owner = 16 * g + ks / 3;
    const int ms = ks - 3 * (ks / 3);
    const float v0 = __shfl(apb0, owner), v1 = __shfl(apb1, owner), v2 = __shfl(apb2, owner);
    nv = (ms == 0) ? v0 : (ms == 1) ? v1 : v2;
    const float sx0 = __shfl(ax0, owner), sx1 = __shfl(ax1, owner), sx2 = __shfl(ax2, owner);
    const float sy0 = __shfl(ay0, owner), sy1 = __shfl(ay1, owner), sy2 = __shfl(ay2, owner);
    const float sz0 = __shfl(az0, owner), sz1 = __shfl(az1, owner), sz2 = __shfl(az2, owner);
    ngx = (ms == 0) ? sx0 : (ms == 1) ? sx1 : sx2;
    ngy = (ms == 0) ? sy0 : (ms == 1) ? sy1 : sy2;
    ngz = (ms == 0) ? sz0 : (ms == 1) ? sz1 : sz2;
  }

  // ---- edge distances: 3 packed pairs (edges 2t,2t+1), exact ref math ----
  float bed = INFINITY, bvx = 0.f, bvy = 0.f, bvz = 0.f;
  {
    const f32x2 Px = {px, px}, Py = {py, py}, Pz = {pz, pz};
    #pragma unroll
    for (int t = 0; t < 3; ++t) {
      f32x2 X1, Y1, Z1, X2, Y2, Z2;
      if (t == 0) {
        X1 = f32x2{Ea.x, Ea.w}; Y1 = f32x2{Ea.y, Eb.x}; Z1 = f32x2{Ea.z, Eb.y};
        X2 = f32x2{Fa.x, Fa.w}; Y2 = f32x2{Fa.y, Fb.x}; Z2 = f32x2{Fa.z, Fb.y};
      } else if (t == 1) {
        X1 = f32x2{Eb.z, Ec.y}; Y1 = f32x2{Eb.w, Ec.z}; Z1 = f32x2{Ec.x, Ec.w};
        X2 = f32x2{Fb.z, Fc.y}; Y2 = f32x2{Fb.w, Fc.z}; Z2 = f32x2{Fc.x, Fc.w};
      } else {
        X1 = f32x2{Ed.x, Ed.w}; Y1 = f32x2{Ed.y, Ee.x}; Z1 = f32x2{Ed.z, Ee.y};
        X2 = f32x2{Fd.x, Fd.w}; Y2 = f32x2{Fd.y, Fe.x}; Z2 = f32x2{Fd.z, Fe.y};
      }
      const f32x2 dx = pksub(X2, X1), dy = pksub(Y2, Y1), dz = pksub(Z2, Z1);
      const f32x2 den = pkadd(pkadd(pkmul(dx, dx), pkmul(dy, dy)), pkmul(dz, dz));
      const f32x2 wx = pksub(Px, X1), wy = pksub(Py, Y1), wz = pksub(Pz, Z1);
      const f32x2 num = pkadd(pkadd(pkmul(wx, dx), pkmul(wy, dy)), pkmul(wz, dz));
      const float th0 = num.x / den.x;             // exact IEEE divs (ref)
      const float th1 = num.y / den.y;
      const float t0 = th0 < 0.0f ? 0.0f : (th0 > 1.0f ? 1.0f : th0);
      const float t1 = th1 < 0.0f ? 0.0f : (th1 > 1.0f ? 1.0f : th1);
      const f32x2 tv = {t0, t1};
      const f32x2 Vx = pkadd(X1, pkmul(tv, dx));   // ref: v1 + t*d
      const f32x2 Vy = pkadd(Y1, pkmul(tv, dy));
      const f32x2 Vz = pkadd(Z1, pkmul(tv, dz));
      const f32x2 Ex = pksub(Px, Vx), Ey = pksub(Py, Vy), Ez = pksub(Pz, Vz);
      const f32x2 ss = pkadd(pkadd(pkmul(Ex, Ex), pkmul(Ey, Ey)), pkmul(Ez, Ez));
      const float ed0 = sqrtf(ss.x);
      const float ed1 = sqrtf(ss.y);
      const bool pick = ed1 < ed0;                 // tie -> lower index
      const float edp = pick ? ed1 : ed0;
      if (edp < bed) {                             // strict -> first index
        bed = edp;
        bvx = pick ? Vx.y : Vx.x;
        bvy = pick ? Vy.y : Vy.x;
        bvz = pick ? Vz.y : Vz.x;
      }
    }
  }
  // ---- edge reduction: f32 value-min butterfly + ballot/ctz winner ----
  float m = bed;
  #pragma unroll
  for (int off = 8; off; off >>= 1) {
    const float o = __shfl_xor(m, off);
    m = fminf(m, o);
  }
  const u64 cand = __ballot(bed == m);             // per-group fields
  const u32 gf = (u32)((cand >> (16 * g)) & 0xFFFFu);
  const int wl = 16 * g + __builtin_ctz(gf);       // first winner (index order)
  const float wvx = __shfl(bvx, wl);
  const float wvy = __shfl(bvy, wl);
  const float wvz = __shfl(bvz, wl);

  // ---- combine; lanes j=0..2 write grad comps, j=3 writes dist ----
  const bool isneg = (negbits >> g) & 1;
  const bool use_edge = (m < fv);
  const float pd = (j == 0) ? px : (j == 1) ? py : pz;
  const float wd = (j == 0) ? wvx : (j == 1) ? wvy : wvz;
  const float fd = (j == 0) ? fgx : (j == 1) ? fgy : fgz;
  const float nd = (j == 0) ? ngx : (j == 1) ? ngy : ngz;
  float dist, gnum, gden = 1.0f;
  if (isneg) {
    dist = nv; gnum = nd;
  } else if (use_edge) {
    dist = m; gnum = pd - wd; gden = m;
  } else {
    dist = fv; gnum = fd;
  }
  const float gr = gnum / gden;
  if (j < 3) out[(size_t)N + 3 * (size_t)n + j] = gr;
  if (j == 3) out[n] = dist;
}

extern "C" void kernel_launch(void* const* d_in, const int* in_sizes, int n_in,
                              void* d_out, int out_size, void* d_ws, size_t ws_size,
                              hipStream_t stream) {
  const float* point = (const float*)d_in[0];
  const float* Ag    = (const float*)d_in[1];
  const float* bg    = (const float*)d_in[2];
  const float* v1g   = (const float*)d_in[3];
  const float* v2g   = (const float*)d_in[4];
  float* out = (float*)d_out;

  const int N = in_sizes[0] / 3;
  const int blocks = (N + PPW - 1) / PPW;   // 4 points per 64-thread block
  zono_dist_kernel<<<blocks, 64, 0, stream>>>(point, Ag, bg, v1g, v2g, out, N);
}